// Round 4
// baseline (586.082 us; speedup 1.0000x reference)
//
#include <hip/hip_runtime.h>
#include <hip/hip_bf16.h>

#define B_N 128
#define T_N 2048
#define H_N 512

typedef __attribute__((ext_vector_type(8))) short bf16x8;   // 8 bf16 = 4 VGPRs
typedef __attribute__((ext_vector_type(4))) float f32x4;    // MFMA acc

union U4 { unsigned int i[4]; bf16x8 v; };

// RNE f32 -> bf16 (low 16 bits)
__device__ __forceinline__ unsigned int f2bf(float f) {
    unsigned int u = __float_as_uint(f);
    u += 0x7fffu + ((u >> 16) & 1u);
    return u >> 16;
}

// packed f32x2 -> bf16x2 (RNE), single VALU inst
__device__ __forceinline__ unsigned int cvtpk(float lo, float hi) {
    unsigned int r;
    asm("v_cvt_pk_bf16_f32 %0, %1, %2" : "=v"(r) : "v"(lo), "v"(hi));
    return r;
}

// x >= 0 always here (relu+relu)
__device__ __forceinline__ float tanh_fast(float x) {
    float e = __expf(2.f * x);
    float r = __builtin_amdgcn_rcpf(e + 1.f);
    return 1.f - 2.f * r;
}

__device__ __forceinline__ void fence_mem() { asm volatile("" ::: "memory"); }

// ---------------------------------------------------------------------------
// K2: w2 (512x512 f32) -> bf16, pre-swizzled within each 1024B row:
// dst_byte(g,k) = g*1024 + ((k*2) ^ ((g&7)<<4)). Staged LINEARLY into LDS;
// fragment read applies byte^((row&7)<<4), cancelling (even swizzle count).
// ---------------------------------------------------------------------------
__global__ void k_w2prep(const float* __restrict__ w2, unsigned short* __restrict__ w2sw) {
    int c = blockIdx.x * 256 + threadIdx.x;      // 32768 chunks of 8 elems
    int g = c >> 6, kc = c & 63;
    const float4* s = reinterpret_cast<const float4*>(w2 + (size_t)g * H_N + kc * 8);
    float4 f0 = s[0], f1 = s[1];
    uint4 p;
    p.x = f2bf(f0.x) | (f2bf(f0.y) << 16);
    p.y = f2bf(f0.z) | (f2bf(f0.w) << 16);
    p.z = f2bf(f1.x) | (f2bf(f1.y) << 16);
    p.w = f2bf(f1.z) | (f2bf(f1.w) << 16);
    *reinterpret_cast<uint4*>(reinterpret_cast<char*>(w2sw) + (size_t)g * 1024 +
                              (((kc * 16) ^ ((g & 7) << 4)))) = p;
}

// ---------------------------------------------------------------------------
// K1: q_h[b][g] = relu(query[b]·w1[g])   (f32, tiny; w1 L2-resident)
// ---------------------------------------------------------------------------
__global__ void k_qh(const float* __restrict__ query, const float* __restrict__ w1,
                     float* __restrict__ qh) {
    int b = blockIdx.x;
    int g = threadIdx.x;                          // 512 threads
    __shared__ float q[H_N];
    q[g] = query[(size_t)b * H_N + g];
    __syncthreads();
    const float4* w = reinterpret_cast<const float4*>(w1 + (size_t)g * H_N);
    float acc = 0.f;
#pragma unroll 4
    for (int i = 0; i < H_N / 4; ++i) {
        float4 wv = w[i];
        acc += q[4*i] * wv.x + q[4*i+1] * wv.y + q[4*i+2] * wv.z + q[4*i+3] * wv.w;
    }
    qh[(size_t)b * H_N + g] = fmaxf(acc, 0.f);
}

// ---------------------------------------------------------------------------
// K3: scores[b][t] = sum_g w_out[g]*tanh(qh[b][g] + relu(key[b][t]·w2[g]))
// BM=128 t-rows/block; 4 N-sweeps of 128 g; BK=64, 8 K-steps/sweep = 32 steps.
// 8 waves: wr=wid>>2 (t half, 64 rows), wc=wid&3 (32-g quarter); per wave
// 4m x 2n frags of 16x16x32. Pipeline (T3/T4 minimum recipe, counted vmcnt):
//   A (key, HBM): f32 via global_load_lds, DOUBLE-buffered, issued 2 steps
//     ahead (src-side XOR swizzle slot^(row&7), 16 slots/row).
//   B (w2sw, L2): single 16KB buffer, staged after barrier1, linear copy of
//     pre-swizzled rows.
// Per step: compute | bar1 | stageB(s+1) | stageA(s+2) | vmcnt(4) | bar2.
// vmcnt(4) leaves exactly the 4 newest loads (A(s+2)) in flight.
// LDS 80KB -> 2 blocks/CU; VGPR ~100 (<=128 for 2 blocks).
// ---------------------------------------------------------------------------
__global__ __launch_bounds__(512, 4) void k_scores(
    const float* __restrict__ key, const unsigned short* __restrict__ w2sw,
    const float* __restrict__ qh, const float* __restrict__ w_out,
    float* __restrict__ scores)
{
    const int b    = blockIdx.y;
    const int t0   = blockIdx.x * 128;
    const int tid  = threadIdx.x;
    const int wid  = tid >> 6;
    const int lane = tid & 63;
    const int lrow = lane & 15;        // fragment row/col
    const int lq   = lane >> 4;        // 0..3 k-group
    const int wr   = wid >> 2;         // 0..1 t half
    const int wc   = wid & 3;          // 0..3 g quarter (of 128)
    const int swz8 = lrow & 7;         // == (tile_row & 7) for all frag rows
    const int swzB = swz8 << 4;        // byte XOR for B reads

    __shared__ __align__(16) char smem[81920];   // [0,64K): A dbuf f32; [64K,80K): B bf16
    char* Af = smem;
    char* Bf = smem + 65536;
    float* sscore = reinterpret_cast<float*>(smem);  // aliases A buf0, used post-loop

    const char* keybB = reinterpret_cast<const char*>(key + ((size_t)b * T_N + t0) * H_N);
    const char* w2sb  = reinterpret_cast<const char*>(w2sw);

    // ---- preload per-thread epilogue constants (keeps loop free of vmem) ----
    float wo_r[4][2], qh_r[4][2];
#pragma unroll
    for (int sw = 0; sw < 4; ++sw)
#pragma unroll
        for (int n = 0; n < 2; ++n) {
            int g = sw * 128 + wc * 32 + n * 16 + lrow;
            wo_r[sw][n] = w_out[g];
            qh_r[sw][n] = qh[(size_t)b * H_N + g];
        }

    // A-tile for step u: key rows [t0,t0+128) x f32 cols [(u&7)*64, +64)
    // 2048 16B slots, 4/thread; dst buffer (u&1).
    auto stageA = [&](int u) {
        const int kkB = (u & 7) << 8;            // byte offset of k-tile in row
        char* dst = Af + ((u & 1) << 15);
#pragma unroll
        for (int i = 0; i < 4; ++i) {
            int c0   = i * 512 + wid * 64;       // wave-uniform
            int c    = c0 + lane;
            int row  = c >> 4;
            int slot = c & 15;
            const char* src = keybB + (size_t)row * 2048 + kkB +
                              ((slot ^ (row & 7)) << 4);
            __builtin_amdgcn_global_load_lds(
                (const __attribute__((address_space(1))) void*)src,
                (__attribute__((address_space(3))) void*)(dst + c0 * 16), 16, 0, 0);
        }
    };
    // B-tile for step u: w2sw rows [(u>>3)*128, +128) x bf16 cols [(u&7)*64,+64)
    // 1024 16B slots, 2/thread; linear copy (pre-swizzled source).
    auto stageB = [&](int u) {
        const int g0  = (u >> 3) << 7;
        const int kkB = (u & 7) << 7;            // byte offset of k-tile in row
#pragma unroll
        for (int i = 0; i < 2; ++i) {
            int c0   = i * 512 + wid * 64;       // wave-uniform
            int c    = c0 + lane;
            int row  = c >> 3;
            int slot = c & 7;
            const char* src = w2sb + (size_t)(g0 + row) * 1024 + kkB + slot * 16;
            __builtin_amdgcn_global_load_lds(
                (const __attribute__((address_space(1))) void*)src,
                (__attribute__((address_space(3))) void*)(Bf + c0 * 16), 16, 0, 0);
        }
    };

    float pscore[4][4] = {};        // [m][r] partials over all g
    f32x4 acc[4][2];
#pragma unroll
    for (int m = 0; m < 4; ++m)
#pragma unroll
        for (int n = 0; n < 2; ++n) acc[m][n] = f32x4{0.f, 0.f, 0.f, 0.f};

    // ---- prologue: A(0), B(0), A(1) in flight; wait A(0)+B(0) ----
    stageA(0);
    stageB(0);
    stageA(1);
    asm volatile("s_waitcnt vmcnt(4)" ::: "memory");   // A(1) stays in flight
    __builtin_amdgcn_s_barrier();
    fence_mem();

#pragma unroll
    for (int sw = 0; sw < 4; ++sw) {           // N-sweeps (unrolled: static wo_r/qh_r idx)
        for (int ks = 0; ks < 8; ++ks) {       // K-steps (rolled)
            const int s = sw * 8 + ks;
            const char* Acur = Af + ((s & 1) << 15);

            // ---- compute step s: 2 k-subtiles x (4m x 2n) MFMA ----
#pragma unroll
            for (int ksub = 0; ksub < 2; ++ksub) {
                bf16x8 bv[2];
#pragma unroll
                for (int n = 0; n < 2; ++n) {
                    int row = wc * 32 + n * 16 + lrow;
                    bv[n] = *reinterpret_cast<const bf16x8*>(
                        Bf + row * 128 + ((ksub * 64 + lq * 16) ^ swzB));
                }
#pragma unroll
                for (int m = 0; m < 4; ++m) {
                    int row = wr * 64 + m * 16 + lrow;
                    int sl  = ksub * 8 + lq * 2;
                    const char* base = Acur + row * 256;
                    float4 f0 = *reinterpret_cast<const float4*>(base + ((sl ^ swz8) << 4));
                    float4 f1 = *reinterpret_cast<const float4*>(base + (((sl + 1) ^ swz8) << 4));
                    U4 u;
                    u.i[0] = cvtpk(f0.x, f0.y);
                    u.i[1] = cvtpk(f0.z, f0.w);
                    u.i[2] = cvtpk(f1.x, f1.y);
                    u.i[3] = cvtpk(f1.z, f1.w);
#pragma unroll
                    for (int n = 0; n < 2; ++n)
                        acc[m][n] = __builtin_amdgcn_mfma_f32_16x16x32_bf16(
                            u.v, bv[n], acc[m][n], 0, 0, 0);
                }
            }

            // ---- barrier1: all waves done reading Bf and Acur ----
            fence_mem();
            __builtin_amdgcn_s_barrier();
            fence_mem();

            if (s < 31) stageB(s + 1);          // 2 loads (L2-hot)
            if (s < 30) stageA(s + 2);          // 4 loads (HBM, 2 steps of budget)

            if (ks == 7) {
                // ---- sweep epilogue (registers only; overlaps DMA) ----
#pragma unroll
                for (int n = 0; n < 2; ++n) {
                    float wo = wo_r[sw][n];
                    float qv = qh_r[sw][n];
#pragma unroll
                    for (int m = 0; m < 4; ++m) {
#pragma unroll
                        for (int r = 0; r < 4; ++r) {
                            float x = qv + fmaxf(acc[m][n][r], 0.f);
                            pscore[m][r] = fmaf(wo, tanh_fast(x), pscore[m][r]);
                        }
                        acc[m][n] = f32x4{0.f, 0.f, 0.f, 0.f};
                    }
                }
            }

            // ---- barrier2: A(s+1)+B(s+1) landed; A(s+2) stays in flight ----
            if (s < 30) {
                asm volatile("s_waitcnt vmcnt(4)" ::: "memory");
                __builtin_amdgcn_s_barrier();
                fence_mem();
            } else if (s == 30) {
                asm volatile("s_waitcnt vmcnt(0)" ::: "memory");
                __builtin_amdgcn_s_barrier();
                fence_mem();
            }
        }
    }

    // ---- reduce over 16 fragment columns (lanes), then across g-waves ----
#pragma unroll
    for (int m = 0; m < 4; ++m)
#pragma unroll
        for (int r = 0; r < 4; ++r) {
            float v = pscore[m][r];
            v += __shfl_xor(v, 1);
            v += __shfl_xor(v, 2);
            v += __shfl_xor(v, 4);
            v += __shfl_xor(v, 8);
            if (lrow == 0)
                sscore[wc * 128 + wr * 64 + m * 16 + lq * 4 + r] = v;
        }
    __syncthreads();
    if (tid < 128)
        scores[(size_t)b * T_N + t0 + tid] =
            sscore[0 * 128 + tid] + sscore[1 * 128 + tid] +
            sscore[2 * 128 + tid] + sscore[3 * 128 + tid];
}

// ---------------------------------------------------------------------------
// K4: softmax over T per batch row (f32)
// ---------------------------------------------------------------------------
__global__ void k_softmax(const float* __restrict__ scores, float* __restrict__ attn) {
    int b = blockIdx.x, tid = threadIdx.x;      // 256 threads, 8 elems each
    __shared__ float red[256];
    float v[8];
    float mx = -3.4e38f;
#pragma unroll
    for (int i = 0; i < 8; ++i) {
        v[i] = scores[(size_t)b * T_N + i * 256 + tid];
        mx = fmaxf(mx, v[i]);
    }
    red[tid] = mx; __syncthreads();
    for (int s = 128; s > 0; s >>= 1) {
        if (tid < s) red[tid] = fmaxf(red[tid], red[tid + s]);
        __syncthreads();
    }
    mx = red[0];
    __syncthreads();
    float sum = 0.f;
#pragma unroll
    for (int i = 0; i < 8; ++i) { v[i] = __expf(v[i] - mx); sum += v[i]; }
    red[tid] = sum; __syncthreads();
    for (int s = 128; s > 0; s >>= 1) {
        if (tid < s) red[tid] += red[tid + s];
        __syncthreads();
    }
    float inv = 1.f / red[0];
#pragma unroll
    for (int i = 0; i < 8; ++i)
        attn[(size_t)b * T_N + i * 256 + tid] = v[i] * inv;
}

// ---------------------------------------------------------------------------
// K5: partial[b][c][h] = sum_{t in chunk c} attn[b][t] * key[b][t][h]
// ---------------------------------------------------------------------------
__global__ void k_wsum(const float* __restrict__ key, const float* __restrict__ attn,
                       float* __restrict__ partial) {
    int c = blockIdx.x, b = blockIdx.y, tid = threadIdx.x; // 256 threads
    __shared__ float at[128];
    if (tid < 128) at[tid] = attn[(size_t)b * T_N + c * 128 + tid];
    __syncthreads();
    const float2* kp = reinterpret_cast<const float2*>(
        key + ((size_t)b * T_N + (size_t)c * 128) * H_N) + tid;
    float ax = 0.f, ay = 0.f;
#pragma unroll 4
    for (int t = 0; t < 128; ++t) {
        float2 kv = kp[(size_t)t * 256];
        float a = at[t];
        ax = fmaf(a, kv.x, ax);
        ay = fmaf(a, kv.y, ay);
    }
    float2 o; o.x = ax; o.y = ay;
    *reinterpret_cast<float2*>(partial + ((size_t)(b * 16 + c)) * H_N + tid * 2) = o;
}

// ---------------------------------------------------------------------------
// K6: out[b][h] = sum_c partial[b][c][h]
// ---------------------------------------------------------------------------
__global__ void k_reduce(const float* __restrict__ partial, float* __restrict__ out) {
    int idx = blockIdx.x * 256 + threadIdx.x;   // 65536 outputs
    int b = idx >> 9, h = idx & 511;
    float s = 0.f;
#pragma unroll
    for (int c = 0; c < 16; ++c) s += partial[((size_t)(b * 16 + c)) * H_N + h];
    out[idx] = s;
}

extern "C" void kernel_launch(void* const* d_in, const int* in_sizes, int n_in,
                              void* d_out, int out_size, void* d_ws, size_t ws_size,
                              hipStream_t stream) {
    const float* query = (const float*)d_in[0];
    const float* key   = (const float*)d_in[1];
    const float* w1    = (const float*)d_in[2];
    const float* w2    = (const float*)d_in[3];
    const float* w_out = (const float*)d_in[4];
    float* out = (float*)d_out;

    char* ws = (char*)d_ws;
    unsigned short* w2sw = (unsigned short*)(ws);            // 512 KB
    float* qh      = (float*)(ws + 524288);                  // 256 KB
    float* scores  = (float*)(ws + 786432);                  // 1 MB
    float* attn    = (float*)(ws + 1835008);                 // 1 MB
    float* partial = (float*)(ws + 2883584);                 // 4 MB

    hipLaunchKernelGGL(k_w2prep,  dim3(128),      dim3(256), 0, stream, w2, w2sw);
    hipLaunchKernelGGL(k_qh,      dim3(128),      dim3(512), 0, stream, query, w1, qh);
    hipLaunchKernelGGL(k_scores,  dim3(16, 128),  dim3(512), 0, stream, key, w2sw, qh, w_out, scores);
    hipLaunchKernelGGL(k_softmax, dim3(128),      dim3(256), 0, stream, scores, attn);
    hipLaunchKernelGGL(k_wsum,    dim3(16, 128),  dim3(256), 0, stream, key, attn, partial);
    hipLaunchKernelGGL(k_reduce,  dim3(256),      dim3(256), 0, stream, partial, out);
}

// Round 5
// 387.477 us; speedup vs baseline: 1.5126x; 1.5126x over previous
//
#include <hip/hip_runtime.h>
#include <hip/hip_bf16.h>

#define B_N 128
#define T_N 2048
#define H_N 512

typedef __attribute__((ext_vector_type(8))) short bf16x8;   // 8 bf16 = 4 VGPRs
typedef __attribute__((ext_vector_type(4))) float f32x4;    // MFMA acc

union U4 { unsigned int i[4]; bf16x8 v; };

// RNE f32 -> bf16 (low 16 bits)
__device__ __forceinline__ unsigned int f2bf(float f) {
    unsigned int u = __float_as_uint(f);
    u += 0x7fffu + ((u >> 16) & 1u);
    return u >> 16;
}

// packed f32x2 -> bf16x2 (RNE), single VALU inst
__device__ __forceinline__ unsigned int cvtpk(float lo, float hi) {
    unsigned int r;
    asm("v_cvt_pk_bf16_f32 %0, %1, %2" : "=v"(r) : "v"(lo), "v"(hi));
    return r;
}

// x >= 0 always here (relu+relu)
__device__ __forceinline__ float tanh_fast(float x) {
    float e = __expf(2.f * x);
    float r = __builtin_amdgcn_rcpf(e + 1.f);
    return 1.f - 2.f * r;
}

__device__ __forceinline__ void fence_mem() { asm volatile("" ::: "memory"); }

// ---------------------------------------------------------------------------
// K2: w2 (512x512 f32) -> bf16, pre-swizzled within each 1024B row:
// dst_byte(g,k) = g*1024 + ((k*2) ^ ((g&7)<<4)). Staged LINEARLY into LDS;
// fragment read applies byte^((row&7)<<4), cancelling (even swizzle count).
// ---------------------------------------------------------------------------
__global__ void k_w2prep(const float* __restrict__ w2, unsigned short* __restrict__ w2sw) {
    int c = blockIdx.x * 256 + threadIdx.x;      // 32768 chunks of 8 elems
    int g = c >> 6, kc = c & 63;
    const float4* s = reinterpret_cast<const float4*>(w2 + (size_t)g * H_N + kc * 8);
    float4 f0 = s[0], f1 = s[1];
    uint4 p;
    p.x = f2bf(f0.x) | (f2bf(f0.y) << 16);
    p.y = f2bf(f0.z) | (f2bf(f0.w) << 16);
    p.z = f2bf(f1.x) | (f2bf(f1.y) << 16);
    p.w = f2bf(f1.z) | (f2bf(f1.w) << 16);
    *reinterpret_cast<uint4*>(reinterpret_cast<char*>(w2sw) + (size_t)g * 1024 +
                              (((kc * 16) ^ ((g & 7) << 4)))) = p;
}

// ---------------------------------------------------------------------------
// K1: q_h[b][g] = relu(query[b]·w1[g])   (f32, tiny; w1 L2-resident)
// ---------------------------------------------------------------------------
__global__ void k_qh(const float* __restrict__ query, const float* __restrict__ w1,
                     float* __restrict__ qh) {
    int b = blockIdx.x;
    int g = threadIdx.x;                          // 512 threads
    __shared__ float q[H_N];
    q[g] = query[(size_t)b * H_N + g];
    __syncthreads();
    const float4* w = reinterpret_cast<const float4*>(w1 + (size_t)g * H_N);
    float acc = 0.f;
#pragma unroll 4
    for (int i = 0; i < H_N / 4; ++i) {
        float4 wv = w[i];
        acc += q[4*i] * wv.x + q[4*i+1] * wv.y + q[4*i+2] * wv.z + q[4*i+3] * wv.w;
    }
    qh[(size_t)b * H_N + g] = fmaxf(acc, 0.f);
}

// ---------------------------------------------------------------------------
// K3 (fused): per block of 128 t-rows:
//   s_t   = sum_g w_out[g]*tanh(qh[b][g] + relu(key[b][t]·w2[g]))   (MFMA)
//   w_t   = exp(s_t)          (NO max subtraction: |s| <= Sum|w_out| ~ 15,
//                              softmax is shift-invariant, e^±15 safe in f32)
//   psum[b][c]       = sum_t w_t
//   partial[b][c][h] = sum_t w_t * key[t][h]   (key tile is L2/L3-hot)
// GEMM: BM=128, BN=256 (2 sweeps), BK=64 (16 steps). 8 waves, wave tile
// 64t x 64g, 4x4 frags of 16x16x32. A (key f32) and B (w2sw bf16) BOTH
// double-buffered via global_load_lds, staged 2 STEPS AHEAD, counted
// vmcnt(8) (never 0 mid-loop). LDS 128 KB -> 1 block/CU (m201-style).
// ---------------------------------------------------------------------------
__global__ __launch_bounds__(512, 2) void k_scores(
    const float* __restrict__ key, const unsigned short* __restrict__ w2sw,
    const float* __restrict__ qh, const float* __restrict__ w_out,
    float* __restrict__ partial, float* __restrict__ psum)
{
    const int b    = blockIdx.y;
    const int chnk = blockIdx.x;
    const int t0   = chnk * 128;
    const int tid  = threadIdx.x;
    const int wid  = tid >> 6;
    const int lane = tid & 63;
    const int lrow = lane & 15;        // fragment row/col
    const int lq   = lane >> 4;        // 0..3 k-group
    const int wr   = wid >> 2;         // 0..1 t half
    const int wc   = wid & 3;          // 0..3 g quarter (of 256)
    const int swz8 = lrow & 7;         // == (tile_row & 7) for all frag rows
    const int swzB = swz8 << 4;        // byte XOR for B reads

    // [0,64K): A f32 dbuf (2 x 128rows x 64k x 4B); [64K,128K): B bf16 dbuf
    __shared__ __align__(16) char smem[131072];
    float* sscore = reinterpret_cast<float*>(smem);          // post-loop alias
    float* wlds   = reinterpret_cast<float*>(smem + 2048);   // post-loop alias

    const char* keybB = reinterpret_cast<const char*>(key + ((size_t)b * T_N + t0) * H_N);
    const char* w2sb  = reinterpret_cast<const char*>(w2sw);

    // ---- preload per-thread epilogue constants (keeps loop free of vmem) ----
    float wo_r[2][4], qh_r[2][4];
#pragma unroll
    for (int sw = 0; sw < 2; ++sw)
#pragma unroll
        for (int n = 0; n < 4; ++n) {
            int g = sw * 256 + wc * 64 + n * 16 + lrow;
            wo_r[sw][n] = w_out[g];
            qh_r[sw][n] = qh[(size_t)b * H_N + g];
        }

    // A-tile step u: key rows [t0,+128) x f32 cols [(u&7)*64,+64); buf u&1.
    // Source-side XOR swizzle (slot^(row&7)); LDS dest linear. 4 loads/thread.
    auto stageA = [&](int u) {
        const int kkB = (u & 7) << 8;
        char* dst = smem + ((u & 1) << 15);
#pragma unroll
        for (int i = 0; i < 4; ++i) {
            int c0   = i * 512 + wid * 64;       // wave-uniform
            int c    = c0 + lane;
            int row  = c >> 4;
            int slot = c & 15;
            const char* src = keybB + (size_t)row * 2048 + kkB +
                              ((slot ^ (row & 7)) << 4);
            __builtin_amdgcn_global_load_lds(
                (const __attribute__((address_space(1))) void*)src,
                (__attribute__((address_space(3))) void*)(dst + c0 * 16), 16, 0, 0);
        }
    };
    // B-tile step u: w2sw rows [(u>>3)*256,+256) x bf16 cols [(u&7)*64,+64);
    // buf u&1. Linear copy of pre-swizzled rows. 4 loads/thread.
    auto stageB = [&](int u) {
        const int g0  = (u >> 3) << 8;
        const int kkB = (u & 7) << 7;
        char* dst = smem + 65536 + ((u & 1) << 15);
#pragma unroll
        for (int i = 0; i < 4; ++i) {
            int c0   = i * 512 + wid * 64;       // wave-uniform
            int c    = c0 + lane;
            int row  = c >> 3;
            int slot = c & 7;
            const char* src = w2sb + (size_t)(g0 + row) * 1024 + kkB + slot * 16;
            __builtin_amdgcn_global_load_lds(
                (const __attribute__((address_space(1))) void*)src,
                (__attribute__((address_space(3))) void*)(dst + c0 * 16), 16, 0, 0);
        }
    };

    float pscore[4][4] = {};        // [m][r] partials over all g
    f32x4 acc[4][4];
#pragma unroll
    for (int m = 0; m < 4; ++m)
#pragma unroll
        for (int n = 0; n < 4; ++n) acc[m][n] = f32x4{0.f, 0.f, 0.f, 0.f};

    // ---- prologue: steps 0 and 1 staged; wait step 0 (8 newest remain) ----
    stageA(0); stageB(0);
    stageA(1); stageB(1);
    asm volatile("s_waitcnt vmcnt(8)" ::: "memory");
    __builtin_amdgcn_s_barrier();
    fence_mem();

    for (int s = 0; s < 16; ++s) {
        const char* Acur = smem + ((s & 1) << 15);
        const char* Bcur = smem + 65536 + ((s & 1) << 15);

        // ---- compute step s: 2 k-subtiles x (4m x 4n) MFMA ----
#pragma unroll
        for (int ksub = 0; ksub < 2; ++ksub) {
            bf16x8 bv[4];
#pragma unroll
            for (int n = 0; n < 4; ++n) {
                int row = wc * 64 + n * 16 + lrow;
                bv[n] = *reinterpret_cast<const bf16x8*>(
                    Bcur + row * 128 + ((ksub * 64 + lq * 16) ^ swzB));
            }
#pragma unroll
            for (int m = 0; m < 4; ++m) {
                int row = wr * 64 + m * 16 + lrow;
                int sl  = ksub * 8 + lq * 2;
                const char* base = Acur + row * 256;
                float4 f0 = *reinterpret_cast<const float4*>(base + ((sl ^ swz8) << 4));
                float4 f1 = *reinterpret_cast<const float4*>(base + (((sl + 1) ^ swz8) << 4));
                U4 u;
                u.i[0] = cvtpk(f0.x, f0.y);
                u.i[1] = cvtpk(f0.z, f0.w);
                u.i[2] = cvtpk(f1.x, f1.y);
                u.i[3] = cvtpk(f1.z, f1.w);
#pragma unroll
                for (int n = 0; n < 4; ++n)
                    acc[m][n] = __builtin_amdgcn_mfma_f32_16x16x32_bf16(
                        u.v, bv[n], acc[m][n], 0, 0, 0);
            }
        }

        // ---- all waves done reading buf (s&1); safe to overwrite it ----
        fence_mem();
        __builtin_amdgcn_s_barrier();
        fence_mem();

        if (s <= 13) { stageA(s + 2); stageB(s + 2); }   // 8 loads, 2 steps ahead

        if (s == 7) {
            // ---- sweep-0 epilogue (registers only; overlaps DMA) ----
#pragma unroll
            for (int n = 0; n < 4; ++n) {
                float wo = wo_r[0][n];
                float qv = qh_r[0][n];
#pragma unroll
                for (int m = 0; m < 4; ++m) {
#pragma unroll
                    for (int r = 0; r < 4; ++r) {
                        float x = qv + fmaxf(acc[m][n][r], 0.f);
                        pscore[m][r] = fmaf(wo, tanh_fast(x), pscore[m][r]);
                    }
                    acc[m][n] = f32x4{0.f, 0.f, 0.f, 0.f};
                }
            }
        }

        // ---- wait: step s+1 landed; step s+2's 8 loads stay in flight ----
        if (s <= 13) {
            asm volatile("s_waitcnt vmcnt(8)" ::: "memory");
            __builtin_amdgcn_s_barrier();
            fence_mem();
        } else if (s == 14) {
            asm volatile("s_waitcnt vmcnt(0)" ::: "memory");
            __builtin_amdgcn_s_barrier();
            fence_mem();
        } else {
            __builtin_amdgcn_s_barrier();   // s==15: LDS reads done; smem reusable
            fence_mem();
        }
    }

    // ---- sweep-1 epilogue ----
#pragma unroll
    for (int n = 0; n < 4; ++n) {
        float wo = wo_r[1][n];
        float qv = qh_r[1][n];
#pragma unroll
        for (int m = 0; m < 4; ++m)
#pragma unroll
            for (int r = 0; r < 4; ++r) {
                float x = qv + fmaxf(acc[m][n][r], 0.f);
                pscore[m][r] = fmaf(wo, tanh_fast(x), pscore[m][r]);
            }
    }

    // ---- cross-lane (16 g-cols) then cross-wave (4 wc) score reduction ----
#pragma unroll
    for (int m = 0; m < 4; ++m)
#pragma unroll
        for (int r = 0; r < 4; ++r) {
            float v = pscore[m][r];
            v += __shfl_xor(v, 1);
            v += __shfl_xor(v, 2);
            v += __shfl_xor(v, 4);
            v += __shfl_xor(v, 8);
            if (lrow == 0)
                sscore[wc * 128 + wr * 64 + m * 16 + lq * 4 + r] = v;
        }
    __syncthreads();

    // ---- w_t = exp(s_t) (no max-sub; see header) ----
    if (tid < 128)
        wlds[tid] = __expf(sscore[0 * 128 + tid] + sscore[1 * 128 + tid] +
                           sscore[2 * 128 + tid] + sscore[3 * 128 + tid]);
    __syncthreads();

    // ---- psum (wave 0) + weighted key sum (all 512 threads, h = tid) ----
    if (wid == 0) {
        float v = wlds[lane] + wlds[lane + 64];
        v += __shfl_xor(v, 1);
        v += __shfl_xor(v, 2);
        v += __shfl_xor(v, 4);
        v += __shfl_xor(v, 8);
        v += __shfl_xor(v, 16);
        v += __shfl_xor(v, 32);
        if (lane == 0) psum[b * 16 + chnk] = v;
    }
    const float* keyp = key + ((size_t)b * T_N + t0) * H_N + tid;
    float a0 = 0.f;
#pragma unroll 8
    for (int t = 0; t < 128; ++t)
        a0 = fmaf(wlds[t], keyp[(size_t)t * H_N], a0);
    partial[((size_t)(b * 16 + chnk)) * H_N + tid] = a0;
}

// ---------------------------------------------------------------------------
// K4: out[b][h] = (sum_c partial[b][c][h]) / (sum_c psum[b][c])
// ---------------------------------------------------------------------------
__global__ void k_out(const float* __restrict__ partial, const float* __restrict__ psum,
                      float* __restrict__ out) {
    int idx = blockIdx.x * 256 + threadIdx.x;   // 65536 outputs
    int b = idx >> 9, h = idx & 511;
    float s = 0.f, d = 0.f;
#pragma unroll
    for (int c = 0; c < 16; ++c) {
        s += partial[((size_t)(b * 16 + c)) * H_N + h];
        d += psum[b * 16 + c];
    }
    out[idx] = s / d;
}

extern "C" void kernel_launch(void* const* d_in, const int* in_sizes, int n_in,
                              void* d_out, int out_size, void* d_ws, size_t ws_size,
                              hipStream_t stream) {
    const float* query = (const float*)d_in[0];
    const float* key   = (const float*)d_in[1];
    const float* w1    = (const float*)d_in[2];
    const float* w2    = (const float*)d_in[3];
    const float* w_out = (const float*)d_in[4];
    float* out = (float*)d_out;

    char* ws = (char*)d_ws;
    unsigned short* w2sw = (unsigned short*)(ws);            // 512 KB
    float* qh      = (float*)(ws + 524288);                  // 256 KB
    float* partial = (float*)(ws + 1048576);                 // 4 MB
    float* psum    = (float*)(ws + 5242880);                 // 8 KB

    hipLaunchKernelGGL(k_w2prep, dim3(128),     dim3(256), 0, stream, w2, w2sw);
    hipLaunchKernelGGL(k_qh,     dim3(128),     dim3(512), 0, stream, query, w1, qh);
    hipLaunchKernelGGL(k_scores, dim3(16, 128), dim3(512), 0, stream,
                       key, w2sw, qh, w_out, partial, psum);
    hipLaunchKernelGGL(k_out,    dim3(256),     dim3(256), 0, stream, partial, psum, out);
}